// Round 5
// baseline (404.572 us; speedup 1.0000x reference)
//
#include <hip/hip_runtime.h>

#define PI_D 3.14159265358979323846

// ---------------------------------------------------------------------------
// Compile-time twiddle tables: CT[k]=cos(2*pi*k/64), STb[k]=sin(2*pi*k/64).
// Full unroll makes every index a constant -> literals folded into the code;
// W^0=(1,0) and W^16=(0,+-1) butterflies simplify at compile time. No LDS.
// ---------------------------------------------------------------------------
namespace {
constexpr float CT[33] = {
  1.0000000000f,  0.9951847267f,  0.9807852804f,  0.9569403357f,
  0.9238795325f,  0.8819212643f,  0.8314696123f,  0.7730104534f,
  0.7071067812f,  0.6343932842f,  0.5555702330f,  0.4713967368f,
  0.3826834324f,  0.2902846773f,  0.1950903220f,  0.0980171403f,
  0.0f,          -0.0980171403f, -0.1950903220f, -0.2902846773f,
 -0.3826834324f, -0.4713967368f, -0.5555702330f, -0.6343932842f,
 -0.7071067812f, -0.7730104534f, -0.8314696123f, -0.8819212643f,
 -0.9238795325f, -0.9569403357f, -0.9807852804f, -0.9951847267f,
 -1.0f};
constexpr float STb[33] = {
  0.0f,           0.0980171403f,  0.1950903220f,  0.2902846773f,
  0.3826834324f,  0.4713967368f,  0.5555702330f,  0.6343932842f,
  0.7071067812f,  0.7730104534f,  0.8314696123f,  0.8819212643f,
  0.9238795325f,  0.9569403357f,  0.9807852804f,  0.9951847267f,
  1.0f,           0.9951847267f,  0.9807852804f,  0.9569403357f,
  0.9238795325f,  0.8819212643f,  0.8314696123f,  0.7730104534f,
  0.7071067812f,  0.6343932842f,  0.5555702330f,  0.4713967368f,
  0.3826834324f,  0.2902846773f,  0.1950903220f,  0.0980171403f,
  0.0f};
}

// In-register 64-point radix-2 DIT FFT, twiddles as literals.
template <bool INV>
__device__ __forceinline__ void fft64_regs(float re[64], float im[64]) {
#pragma unroll
  for (int i = 0; i < 64; ++i) {
    unsigned j = __brev((unsigned)i) >> 26;
    if ((int)j > i) {
      float tr = re[i]; re[i] = re[j]; re[j] = tr;
      float ti = im[i]; im[i] = im[j]; im[j] = ti;
    }
  }
#pragma unroll
  for (int s = 0; s < 6; ++s) {
    const int half = 1 << s;
    const int m = half << 1;
    const int tstep = 32 >> s;  // 64/m
#pragma unroll
    for (int k = 0; k < 64; k += m) {
#pragma unroll
      for (int j = 0; j < half; ++j) {
        const int ti = j * tstep;  // 0..31, compile-time
        const float wr = CT[ti];
        const float wi = INV ? STb[ti] : -STb[ti];
        const int a = k + j, b = k + j + half;
        const float tr = re[b] * wr - im[b] * wi;
        const float tii = re[b] * wi + im[b] * wr;
        re[b] = re[a] - tr; im[b] = im[a] - tii;
        re[a] = re[a] + tr; im[a] = im[a] + tii;
      }
    }
  }
}

// ---------------------------------------------------------------------------
// K0: frequency-band indices from fbs. idx[0..63]=s_idx, idx[64..127]=e_idx.
// ---------------------------------------------------------------------------
__global__ void k_setup(const float* __restrict__ fbs, int* __restrict__ idx) {
  const int t = threadIdx.x;  // 64 threads
  idx[t]      = (int)floorf((fbs[2 * t]     + 1.0f) * 0.5f * 64.0f);
  idx[64 + t] = (int)floorf((fbs[2 * t + 1] + 1.0f) * 0.5f * 64.0f);
}

// ---------------------------------------------------------------------------
// K1: forward FFT2 per (b,i) image. One wave per image. PLANAR output per
// 32KB slot: active (~8%) -> Fre[4096] @ +0, Fim[4096] @ +16KB; inactive ->
// |F| fp32 @ +0 (attn is the only consumer). After the column FFT, thread t
// holds column t in registers, so plane stores plane[j*64+t] are coalesced
// straight from regs -- NO output transpose. Single 64x65 transpose buffer
// used in two passes (re, im).
// ---------------------------------------------------------------------------
__global__ __launch_bounds__(64) void k_fft_fwd(const float* __restrict__ x,
                                                float* __restrict__ F,
                                                const int* __restrict__ idx) {
  __shared__ float buf[64][65];  // stride 65: (t+j)%32 banks -> 2-way (free)
  const int t = threadIdx.x;
  const int img = blockIdx.x;
  const float* xp = x + ((size_t)img << 12);
#pragma unroll
  for (int k = 0; k < 64; ++k) buf[k][t] = xp[k * 64 + t];  // coalesced stage
  __syncthreads();
  float re[64], im[64];
#pragma unroll
  for (int j = 0; j < 64; ++j) { re[j] = buf[t][j]; im[j] = 0.0f; }  // row t
  fft64_regs<false>(re, im);
  // transpose, two passes through the single buffer (row-private writes)
#pragma unroll
  for (int j = 0; j < 64; ++j) buf[t][j] = re[j];
  __syncthreads();
#pragma unroll
  for (int j = 0; j < 64; ++j) re[j] = buf[j][t];
  __syncthreads();
#pragma unroll
  for (int j = 0; j < 64; ++j) buf[t][j] = im[j];
  __syncthreads();
#pragma unroll
  for (int j = 0; j < 64; ++j) im[j] = buf[j][t];
  fft64_regs<false>(re, im);  // column FFT; thread t now holds column t
  const int b = img >> 6, i = img & 63;
  const int b_s = (b + 32) & 63, i_s = (i + 32) & 63;
  const int s0 = idx[b_s], e0 = idx[64 + b_s];
  float* Fre = F + ((size_t)img << 13);  // slot = 8192 floats
  if ((i_s >= s0) && (i_s < e0)) {  // active: planar complex
    float* Fim = Fre + 4096;
#pragma unroll
    for (int j = 0; j < 64; ++j) {
      Fre[j * 64 + t] = re[j];
      Fim[j * 64 + t] = im[j];
    }
  } else {  // inactive: magnitudes only
#pragma unroll
    for (int j = 0; j < 64; ++j)
      Fre[j * 64 + t] = sqrtf(re[j] * re[j] + im[j] * im[j]);
  }
}

// ---------------------------------------------------------------------------
// K2 v3: attention, hidden dim split 2 ways for TLP. 2048 blocks x 256 thr:
// threads 0..127 = k in [0,32), threads 128..255 = k in [32,64), both halves
// covering the same 128 positions (waves 2,3 load the same m[] addresses as
// waves 0,1 -> L1 hits). Logits are linear in the per-k ReLU outputs, so
// partial logits combine exactly through 3 KB LDS. Per-thread serial FMA work
// halves (2048), wave count doubles (8 waves/SIMD available vs 4) -- R4
// showed Occupancy 24% / VALUBusy 38% on one-thread-per-position.
// m[64] FULLY unrolled (partial unroll spilled to scratch in R2).
// ---------------------------------------------------------------------------
__global__ __launch_bounds__(256) void k_attn(
    const float* __restrict__ F, const float* __restrict__ w1,
    const float* __restrict__ b1, const float* __restrict__ w2,
    const float* __restrict__ b2, const float* __restrict__ f0,
    const float* __restrict__ theta, const float* __restrict__ sigma,
    const float* __restrict__ theta0, const int* __restrict__ idx,
    float* __restrict__ Wc) {
  const int t = threadIdx.x;
  const int half = t >> 7;        // wave-uniform (waves 0,1 vs 2,3)
  const int p = t & 127;
  const int i = blockIdx.x >> 5;  // shifted-space batch==channel
  const int pos = ((blockIdx.x & 31) << 7) + p;
  const int h = pos >> 6, w = pos & 63;
  const int b_f = (i + 32) & 63;
  const int u_f = (h + 32) & 63;
  const int v_f = (w + 32) & 63;
  const int pos_f = (u_f << 6) + v_f;
  const int s0a = idx[i], e0a = idx[64 + i];
  float m[64];
#pragma unroll
  for (int c = 0; c < 64; ++c) {
    const int c_f = (c + 32) & 63;
    const float* base = F + ((size_t)((b_f << 6) + c_f) << 13);
    if (c >= s0a && c < e0a) {  // block-uniform branch
      const float xr = base[pos_f];
      const float xi = base[4096 + pos_f];
      m[c] = sqrtf(xr * xr + xi * xi);
    } else {
      m[c] = base[pos_f];  // precomputed magnitude
    }
  }
  float l0, l1, l2;
  if (half == 0) { l0 = b2[0]; l1 = b2[1]; l2 = b2[2]; }
  else           { l0 = 0.0f;  l1 = 0.0f;  l2 = 0.0f; }
  const int k0 = half << 5;
#pragma unroll 8
  for (int kk = 0; kk < 32; ++kk) {
    const int k = k0 + kk;
    float acc = b1[k];
#pragma unroll
    for (int c = 0; c < 64; ++c) acc = fmaf(w1[(k << 6) + c], m[c], acc);
    float hv = fmaxf(acc, 0.0f);
    l0 = fmaf(w2[k], hv, l0);  // w2 layout [S=3][HID=64]
    l1 = fmaf(w2[64 + k], hv, l1);
    l2 = fmaf(w2[128 + k], hv, l2);
  }
  __shared__ float pl[3][256];
  pl[0][t] = l0; pl[1][t] = l1; pl[2][t] = l2;
  __syncthreads();
  if (half) return;  // half-1 waves done (wave-uniform exit)
  l0 += pl[0][t + 128]; l1 += pl[1][t + 128]; l2 += pl[2][t + 128];
  float mx = fmaxf(l0, fmaxf(l1, l2));
  float e0 = expf(l0 - mx), e1 = expf(l1 - mx), e2 = expf(l2 - mx);
  float inv = 1.0f / (e0 + e1 + e2);
  float aw0 = e0 * inv, aw1 = e1 * inv, aw2 = e2 * inv;
  const float yy = -1.0f + (float)h * (2.0f / 63.0f);
  const float xx = -1.0f + (float)w * (2.0f / 63.0f);
  const float r = sqrtf(xx * xx + yy * yy + 1e-6f);
  const float lr = logf(r);
  const float phi = atan2f(yy, xx);
  float wc = 0.0f;
  const float aws[3] = {aw0, aw1, aw2};
#pragma unroll
  for (int s = 0; s < 3; ++s) {
    const float f0v = f0[s * 64 + i];  // [S][O=1][I]
    const float sgv = sigma[s * 64 + i];
    const float thv = theta[s * 64 + i];
    const float t0v = theta0[s * 64 + i];
    const float ls = logf(sgv);
    const float d1 = lr - logf(f0v);
    const float g1 = expf(-(d1 * d1) / (2.0f * ls * ls));
    const float d2 = phi - thv;
    const float g2 = expf(-(d2 * d2) / (2.0f * t0v * t0v));
    wc = fmaf(g1 * g2, aws[s], wc);
  }
  Wc[((i << 6) + h) * 64 + w] = wc;
}

// ---------------------------------------------------------------------------
// K3: spatial 3x3 conv (wave per output row, shuffle-assembled neighbors)
// FUSED with the inactive-image output write: for the ~92% of (b,i) with
// x_filtered==0, out = (1-mix)*conv_row -- the wave already holds that row,
// so write it for every inactive i. Active images are written by k_ifft_act.
// ---------------------------------------------------------------------------
__global__ __launch_bounds__(256) void k_conv(const float* __restrict__ x,
                                              const float* __restrict__ cw,
                                              const int* __restrict__ idx,
                                              const float* __restrict__ mixp,
                                              float* __restrict__ xsp,
                                              float* __restrict__ out) {
  __shared__ float wsm[576];
  const int t = threadIdx.x;
  for (int q = t; q < 576; q += 256) wsm[q] = cw[q];
  __syncthreads();
  const int lane = t & 63;
  const int wv = t >> 6;
  const int b = blockIdx.x >> 4;
  const int row = ((blockIdx.x & 15) << 2) | wv;
  const float* xb = x + ((size_t)b << 18);
  const int rm = row > 0 ? row - 1 : 0;  // clamped (masked in epilogue)
  const int rp = row < 63 ? row + 1 : 63;
  float P00 = 0.f, P01 = 0.f, P02 = 0.f;
  float P10 = 0.f, P11 = 0.f, P12 = 0.f;
  float P20 = 0.f, P21 = 0.f, P22 = 0.f;
#pragma unroll 4
  for (int ch = 0; ch < 64; ++ch) {
    const float* xc = xb + (ch << 12);
    const float v0 = xc[(rm << 6) + lane];
    const float v1 = xc[(row << 6) + lane];
    const float v2 = xc[(rp << 6) + lane];
    const float* wp = &wsm[ch * 9];
    P00 = fmaf(v0, wp[0], P00);
    P01 = fmaf(v0, wp[1], P01);
    P02 = fmaf(v0, wp[2], P02);
    P10 = fmaf(v1, wp[3], P10);
    P11 = fmaf(v1, wp[4], P11);
    P12 = fmaf(v1, wp[5], P12);
    P20 = fmaf(v2, wp[6], P20);
    P21 = fmaf(v2, wp[7], P21);
    P22 = fmaf(v2, wp[8], P22);
  }
  const float tmask = (row > 0) ? 1.0f : 0.0f;
  const float bmask = (row < 63) ? 1.0f : 0.0f;
  const float Ql = tmask * P00 + P10 + bmask * P20;
  const float Qm = tmask * P01 + P11 + bmask * P21;
  const float Qr = tmask * P02 + P12 + bmask * P22;
  const float fromL = __shfl_up(Ql, 1, 64);
  const float fromR = __shfl_down(Qr, 1, 64);
  float acc = Qm;
  if (lane > 0) acc += fromL;
  if (lane < 63) acc += fromR;
  xsp[((size_t)b << 12) + (row << 6) + lane] = acc;
  // Fused inactive-output epilogue (block-uniform per-i predicate).
  const int b_s = (b + 32) & 63;
  const int s0 = idx[b_s], e0 = idx[64 + b_s];
  const float val = (1.0f - mixp[0]) * acc;
  float* ob = out + ((size_t)b << 18) + (row << 6) + lane;
#pragma unroll 4
  for (int i2 = 0; i2 < 64; ++i2) {
    const int i_s = (i2 + 32) & 63;
    if (!(i_s >= s0 && i_s < e0)) ob[(size_t)i2 << 12] = val;
  }
}

// ---------------------------------------------------------------------------
// K4: ACTIVE images only (~8%): G = F*Wc(shifted)*rowmask; IFFT2; real part;
// mix with conv path. Inactive blocks exit immediately (their output was
// written by k_conv). Same single-buffer two-pass transpose structure as K1;
// output stored straight from registers (coalesced).
// ---------------------------------------------------------------------------
__global__ __launch_bounds__(64) void k_ifft_act(
    const float* __restrict__ F, const float* __restrict__ Wc,
    const float* __restrict__ xsp, const int* __restrict__ idx,
    const float* __restrict__ mixp, float* __restrict__ out) {
  const int img = blockIdx.x;
  const int b = img >> 6, i = img & 63;
  const int b_s = (b + 32) & 63, i_s = (i + 32) & 63;
  const int s0 = idx[b_s], e0 = idx[64 + b_s];
  if (!((i_s >= s0) && (i_s < e0))) return;  // inactive: handled by k_conv
  __shared__ float buf[64][65];
  const int t = threadIdx.x;
  const float* Fre = F + ((size_t)img << 13);
  const float* Fim = Fre + 4096;
  const float* Wcp = Wc + ((size_t)i_s << 12);
  const int v_s = (t + 32) & 63;
  // stage re rows (apply Wc * row-mask during staging)
#pragma unroll
  for (int k = 0; k < 64; ++k) {
    const int u_s = (k + 32) & 63;
    const float wvv = (u_s >= s0 && u_s < e0) ? Wcp[(u_s << 6) + v_s] : 0.0f;
    buf[k][t] = Fre[k * 64 + t] * wvv;
  }
  __syncthreads();
  float re[64], im[64];
#pragma unroll
  for (int j = 0; j < 64; ++j) re[j] = buf[t][j];
  __syncthreads();
#pragma unroll
  for (int k = 0; k < 64; ++k) {
    const int u_s = (k + 32) & 63;
    const float wvv = (u_s >= s0 && u_s < e0) ? Wcp[(u_s << 6) + v_s] : 0.0f;
    buf[k][t] = Fim[k * 64 + t] * wvv;
  }
  __syncthreads();
#pragma unroll
  for (int j = 0; j < 64; ++j) im[j] = buf[t][j];
  fft64_regs<true>(re, im);  // row inverse FFTs
  // transpose (two passes)
#pragma unroll
  for (int j = 0; j < 64; ++j) buf[t][j] = re[j];
  __syncthreads();
#pragma unroll
  for (int j = 0; j < 64; ++j) re[j] = buf[j][t];
  __syncthreads();
#pragma unroll
  for (int j = 0; j < 64; ++j) buf[t][j] = im[j];
  __syncthreads();
#pragma unroll
  for (int j = 0; j < 64; ++j) im[j] = buf[j][t];
  fft64_regs<true>(re, im);  // column inverse FFTs; thread t holds column t
  const float mixv = mixp[0];
  const float sc = mixv * (1.0f / 4096.0f);
  const float om = 1.0f - mixv;
  float* op = out + ((size_t)img << 12);
  const float* xp = xsp + ((size_t)b << 12);
#pragma unroll
  for (int j = 0; j < 64; ++j)
    op[j * 64 + t] = fmaf(sc, re[j], om * xp[j * 64 + t]);
}

// ---------------------------------------------------------------------------
// Workspace layout (~131 MB):
//   [0, 128MB)        F    planar slots: active {Fre,Fim}, inactive {|F|}
//   [+128MB, +129MB)  Wc   float[64*64*64]
//   [+129MB, +130MB)  xsp  float[64*64*64]
//   [+130MB, ...)     idx  int[128]
// ---------------------------------------------------------------------------
extern "C" void kernel_launch(void* const* d_in, const int* in_sizes, int n_in,
                              void* d_out, int out_size, void* d_ws, size_t ws_size,
                              hipStream_t stream) {
  const float* x      = (const float*)d_in[0];
  const float* f0     = (const float*)d_in[1];
  const float* theta  = (const float*)d_in[2];
  const float* sigma  = (const float*)d_in[3];
  const float* theta0 = (const float*)d_in[4];
  const float* fbs    = (const float*)d_in[5];
  const float* mix    = (const float*)d_in[6];
  const float* w1     = (const float*)d_in[7];
  const float* b1     = (const float*)d_in[8];
  const float* w2     = (const float*)d_in[9];
  const float* b2     = (const float*)d_in[10];
  const float* cw     = (const float*)d_in[11];
  float* out = (float*)d_out;
  char* ws = (char*)d_ws;
  float* F   = (float*)(ws);
  float* Wc  = (float*)(ws + 134217728);
  float* xsp = (float*)(ws + 134217728 + 1048576);
  int* idx   = (int*)(ws + 134217728 + 2097152);

  k_setup<<<1, 64, 0, stream>>>(fbs, idx);
  k_fft_fwd<<<4096, 64, 0, stream>>>(x, F, idx);
  k_attn<<<2048, 256, 0, stream>>>(F, w1, b1, w2, b2, f0, theta, sigma, theta0, idx, Wc);
  k_conv<<<1024, 256, 0, stream>>>(x, cw, idx, mix, xsp, out);
  k_ifft_act<<<4096, 64, 0, stream>>>(F, Wc, xsp, idx, mix, out);
}

// Round 6
// 282.405 us; speedup vs baseline: 1.4326x; 1.4326x over previous
//
#include <hip/hip_runtime.h>

#define PI_D 3.14159265358979323846

// ---------------------------------------------------------------------------
// Compile-time twiddle tables: CT[k]=cos(2*pi*k/64), STb[k]=sin(2*pi*k/64).
// ---------------------------------------------------------------------------
namespace {
constexpr float CT[33] = {
  1.0000000000f,  0.9951847267f,  0.9807852804f,  0.9569403357f,
  0.9238795325f,  0.8819212643f,  0.8314696123f,  0.7730104534f,
  0.7071067812f,  0.6343932842f,  0.5555702330f,  0.4713967368f,
  0.3826834324f,  0.2902846773f,  0.1950903220f,  0.0980171403f,
  0.0f,          -0.0980171403f, -0.1950903220f, -0.2902846773f,
 -0.3826834324f, -0.4713967368f, -0.5555702330f, -0.6343932842f,
 -0.7071067812f, -0.7730104534f, -0.8314696123f, -0.8819212643f,
 -0.9238795325f, -0.9569403357f, -0.9807852804f, -0.9951847267f,
 -1.0f};
constexpr float STb[33] = {
  0.0f,           0.0980171403f,  0.1950903220f,  0.2902846773f,
  0.3826834324f,  0.4713967368f,  0.5555702330f,  0.6343932842f,
  0.7071067812f,  0.7730104534f,  0.8314696123f,  0.8819212643f,
  0.9238795325f,  0.9569403357f,  0.9807852804f,  0.9951847267f,
  1.0f,           0.9951847267f,  0.9807852804f,  0.9569403357f,
  0.9238795325f,  0.8819212643f,  0.8314696123f,  0.7730104534f,
  0.7071067812f,  0.6343932842f,  0.5555702330f,  0.4713967368f,
  0.3826834324f,  0.2902846773f,  0.1950903220f,  0.0980171403f,
  0.0f};
}

// In-register 64-point radix-2 DIT FFT, twiddles as literals.
template <bool INV>
__device__ __forceinline__ void fft64_regs(float re[64], float im[64]) {
#pragma unroll
  for (int i = 0; i < 64; ++i) {
    unsigned j = __brev((unsigned)i) >> 26;
    if ((int)j > i) {
      float tr = re[i]; re[i] = re[j]; re[j] = tr;
      float ti = im[i]; im[i] = im[j]; im[j] = ti;
    }
  }
#pragma unroll
  for (int s = 0; s < 6; ++s) {
    const int half = 1 << s;
    const int m = half << 1;
    const int tstep = 32 >> s;  // 64/m
#pragma unroll
    for (int k = 0; k < 64; k += m) {
#pragma unroll
      for (int j = 0; j < half; ++j) {
        const int ti = j * tstep;  // 0..31, compile-time
        const float wr = CT[ti];
        const float wi = INV ? STb[ti] : -STb[ti];
        const int a = k + j, b = k + j + half;
        const float tr = re[b] * wr - im[b] * wi;
        const float tii = re[b] * wi + im[b] * wr;
        re[b] = re[a] - tr; im[b] = im[a] - tii;
        re[a] = re[a] + tr; im[a] = im[a] + tii;
      }
    }
  }
}

// ---------------------------------------------------------------------------
// K0: frequency-band indices from fbs + w1 transpose (w1T[c][k] = w1[k][c])
// so k_attn's c-outer loop reads contiguous wave-uniform 64-float rows.
// ---------------------------------------------------------------------------
__global__ void k_setup(const float* __restrict__ fbs, const float* __restrict__ w1,
                        int* __restrict__ idx, float* __restrict__ w1T) {
  const int t = threadIdx.x;  // 64 threads
  idx[t]      = (int)floorf((fbs[2 * t]     + 1.0f) * 0.5f * 64.0f);
  idx[64 + t] = (int)floorf((fbs[2 * t + 1] + 1.0f) * 0.5f * 64.0f);
  for (int k = 0; k < 64; ++k) w1T[t * 64 + k] = w1[k * 64 + t];
}

// ---------------------------------------------------------------------------
// K1: forward FFT2 per (b,i) image. One wave per image. PLANAR output per
// 32KB slot: active (~8%) -> Fre[4096] @ +0, Fim[4096] @ +16KB; inactive ->
// |F| fp32 @ +0 (attn is the only consumer). Column-FFT results stored
// straight from regs (coalesced). Single 64x65 two-pass transpose buffer.
// ---------------------------------------------------------------------------
__global__ __launch_bounds__(64) void k_fft_fwd(const float* __restrict__ x,
                                                float* __restrict__ F,
                                                const int* __restrict__ idx) {
  __shared__ float buf[64][65];  // stride 65: (t+j)%32 banks -> 2-way (free)
  const int t = threadIdx.x;
  const int img = blockIdx.x;
  const float* xp = x + ((size_t)img << 12);
#pragma unroll
  for (int k = 0; k < 64; ++k) buf[k][t] = xp[k * 64 + t];  // coalesced stage
  __syncthreads();
  float re[64], im[64];
#pragma unroll
  for (int j = 0; j < 64; ++j) { re[j] = buf[t][j]; im[j] = 0.0f; }  // row t
  fft64_regs<false>(re, im);
  // transpose, two passes through the single buffer (row-private writes)
#pragma unroll
  for (int j = 0; j < 64; ++j) buf[t][j] = re[j];
  __syncthreads();
#pragma unroll
  for (int j = 0; j < 64; ++j) re[j] = buf[j][t];
  __syncthreads();
#pragma unroll
  for (int j = 0; j < 64; ++j) buf[t][j] = im[j];
  __syncthreads();
#pragma unroll
  for (int j = 0; j < 64; ++j) im[j] = buf[j][t];
  fft64_regs<false>(re, im);  // column FFT; thread t now holds column t
  const int b = img >> 6, i = img & 63;
  const int b_s = (b + 32) & 63, i_s = (i + 32) & 63;
  const int s0 = idx[b_s], e0 = idx[64 + b_s];
  float* Fre = F + ((size_t)img << 13);  // slot = 8192 floats
  if ((i_s >= s0) && (i_s < e0)) {  // active: planar complex
    float* Fim = Fre + 4096;
#pragma unroll
    for (int j = 0; j < 64; ++j) {
      Fre[j * 64 + t] = re[j];
      Fim[j * 64 + t] = im[j];
    }
  } else {  // inactive: magnitudes only
#pragma unroll
    for (int j = 0; j < 64; ++j)
      Fre[j * 64 + t] = sqrtf(re[j] * re[j] + im[j] * im[j]);
  }
}

// ---------------------------------------------------------------------------
// K2 v4: attention. One thread per (i,h,w) position (R4 structure -- R5's
// threadIdx-derived k-split broke s_load uniformity: SGPR 112->32, 2x slower).
// Inner loops SWAPPED vs R4: c-outer / k-inner with 64 independent acc[k]
// chains (ILP=64 instead of 4 -- R4 was 62% stalled on 64-long serial FMA
// chains). w1T rows are loop-induction-addressed -> wave-uniform -> s_load.
// m_c load is branchless (both planes + select; inactive +16KB plane is 0xAA
// poison = tiny float, safe through sqrt) so loads batch without exec branches.
// ---------------------------------------------------------------------------
__global__ __launch_bounds__(256) void k_attn(
    const float* __restrict__ F, const float* __restrict__ w1T,
    const float* __restrict__ b1, const float* __restrict__ w2,
    const float* __restrict__ b2, const float* __restrict__ f0,
    const float* __restrict__ theta, const float* __restrict__ sigma,
    const float* __restrict__ theta0, const int* __restrict__ idx,
    float* __restrict__ Wc) {
  const int i = blockIdx.x >> 4;  // shifted-space batch==channel
  const int pos = ((blockIdx.x & 15) << 8) + threadIdx.x;
  const int h = pos >> 6, w = pos & 63;
  const int b_f = (i + 32) & 63;
  const int u_f = (h + 32) & 63;
  const int v_f = (w + 32) & 63;
  const int pos_f = (u_f << 6) + v_f;
  const int s0a = idx[i], e0a = idx[64 + i];
  float acc[64];
#pragma unroll
  for (int k = 0; k < 64; ++k) acc[k] = 0.0f;
  const float* Fb = F + ((size_t)(b_f << 6) << 13) + pos_f;
#pragma unroll 4
  for (int c = 0; c < 64; ++c) {
    const int c_f = (c + 32) & 63;
    const float* base = Fb + ((size_t)c_f << 13);
    const float xr = base[0];
    const float xi = base[4096];
    const float mag = sqrtf(xr * xr + xi * xi);
    const float mc = (c >= s0a && c < e0a) ? mag : xr;  // branchless select
    const float* wrow = w1T + (c << 6);  // wave-uniform -> s_load
#pragma unroll
    for (int k = 0; k < 64; ++k) acc[k] = fmaf(wrow[k], mc, acc[k]);
  }
  float l0 = b2[0], l1 = b2[1], l2 = b2[2];
#pragma unroll
  for (int k = 0; k < 64; ++k) {
    const float hv = fmaxf(acc[k] + b1[k], 0.0f);
    l0 = fmaf(w2[k], hv, l0);  // w2 layout [S=3][HID=64]
    l1 = fmaf(w2[64 + k], hv, l1);
    l2 = fmaf(w2[128 + k], hv, l2);
  }
  float mx = fmaxf(l0, fmaxf(l1, l2));
  float e0 = expf(l0 - mx), e1 = expf(l1 - mx), e2 = expf(l2 - mx);
  float inv = 1.0f / (e0 + e1 + e2);
  float aw0 = e0 * inv, aw1 = e1 * inv, aw2 = e2 * inv;
  const float yy = -1.0f + (float)h * (2.0f / 63.0f);
  const float xx = -1.0f + (float)w * (2.0f / 63.0f);
  const float r = sqrtf(xx * xx + yy * yy + 1e-6f);
  const float lr = logf(r);
  const float phi = atan2f(yy, xx);
  float wc = 0.0f;
  const float aws[3] = {aw0, aw1, aw2};
#pragma unroll
  for (int s = 0; s < 3; ++s) {
    const float f0v = f0[s * 64 + i];  // [S][O=1][I]
    const float sgv = sigma[s * 64 + i];
    const float thv = theta[s * 64 + i];
    const float t0v = theta0[s * 64 + i];
    const float ls = logf(sgv);
    const float d1 = lr - logf(f0v);
    const float g1 = expf(-(d1 * d1) / (2.0f * ls * ls));
    const float d2 = phi - thv;
    const float g2 = expf(-(d2 * d2) / (2.0f * t0v * t0v));
    wc = fmaf(g1 * g2, aws[s], wc);
  }
  Wc[((i << 6) + h) * 64 + w] = wc;
}

// ---------------------------------------------------------------------------
// K3: spatial 3x3 conv (wave per output row, shuffle-assembled neighbors)
// FUSED with the inactive-image output write: for the ~92% of (b,i) with
// x_filtered==0, out = (1-mix)*conv_row.
// ---------------------------------------------------------------------------
__global__ __launch_bounds__(256) void k_conv(const float* __restrict__ x,
                                              const float* __restrict__ cw,
                                              const int* __restrict__ idx,
                                              const float* __restrict__ mixp,
                                              float* __restrict__ xsp,
                                              float* __restrict__ out) {
  __shared__ float wsm[576];
  const int t = threadIdx.x;
  for (int q = t; q < 576; q += 256) wsm[q] = cw[q];
  __syncthreads();
  const int lane = t & 63;
  const int wv = t >> 6;
  const int b = blockIdx.x >> 4;
  const int row = ((blockIdx.x & 15) << 2) | wv;
  const float* xb = x + ((size_t)b << 18);
  const int rm = row > 0 ? row - 1 : 0;  // clamped (masked in epilogue)
  const int rp = row < 63 ? row + 1 : 63;
  float P00 = 0.f, P01 = 0.f, P02 = 0.f;
  float P10 = 0.f, P11 = 0.f, P12 = 0.f;
  float P20 = 0.f, P21 = 0.f, P22 = 0.f;
#pragma unroll 4
  for (int ch = 0; ch < 64; ++ch) {
    const float* xc = xb + (ch << 12);
    const float v0 = xc[(rm << 6) + lane];
    const float v1 = xc[(row << 6) + lane];
    const float v2 = xc[(rp << 6) + lane];
    const float* wp = &wsm[ch * 9];
    P00 = fmaf(v0, wp[0], P00);
    P01 = fmaf(v0, wp[1], P01);
    P02 = fmaf(v0, wp[2], P02);
    P10 = fmaf(v1, wp[3], P10);
    P11 = fmaf(v1, wp[4], P11);
    P12 = fmaf(v1, wp[5], P12);
    P20 = fmaf(v2, wp[6], P20);
    P21 = fmaf(v2, wp[7], P21);
    P22 = fmaf(v2, wp[8], P22);
  }
  const float tmask = (row > 0) ? 1.0f : 0.0f;
  const float bmask = (row < 63) ? 1.0f : 0.0f;
  const float Ql = tmask * P00 + P10 + bmask * P20;
  const float Qm = tmask * P01 + P11 + bmask * P21;
  const float Qr = tmask * P02 + P12 + bmask * P22;
  const float fromL = __shfl_up(Ql, 1, 64);
  const float fromR = __shfl_down(Qr, 1, 64);
  float acc = Qm;
  if (lane > 0) acc += fromL;
  if (lane < 63) acc += fromR;
  xsp[((size_t)b << 12) + (row << 6) + lane] = acc;
  // Fused inactive-output epilogue (block-uniform per-i predicate).
  const int b_s = (b + 32) & 63;
  const int s0 = idx[b_s], e0 = idx[64 + b_s];
  const float val = (1.0f - mixp[0]) * acc;
  float* ob = out + ((size_t)b << 18) + (row << 6) + lane;
#pragma unroll 4
  for (int i2 = 0; i2 < 64; ++i2) {
    const int i_s = (i2 + 32) & 63;
    if (!(i_s >= s0 && i_s < e0)) ob[(size_t)i2 << 12] = val;
  }
}

// ---------------------------------------------------------------------------
// K4: ACTIVE images only (~8%): G = F*Wc(shifted)*rowmask; IFFT2; real part;
// mix with conv path. Inactive blocks exit immediately.
// ---------------------------------------------------------------------------
__global__ __launch_bounds__(64) void k_ifft_act(
    const float* __restrict__ F, const float* __restrict__ Wc,
    const float* __restrict__ xsp, const int* __restrict__ idx,
    const float* __restrict__ mixp, float* __restrict__ out) {
  const int img = blockIdx.x;
  const int b = img >> 6, i = img & 63;
  const int b_s = (b + 32) & 63, i_s = (i + 32) & 63;
  const int s0 = idx[b_s], e0 = idx[64 + b_s];
  if (!((i_s >= s0) && (i_s < e0))) return;  // inactive: handled by k_conv
  __shared__ float buf[64][65];
  const int t = threadIdx.x;
  const float* Fre = F + ((size_t)img << 13);
  const float* Fim = Fre + 4096;
  const float* Wcp = Wc + ((size_t)i_s << 12);
  const int v_s = (t + 32) & 63;
  // stage re rows (apply Wc * row-mask during staging)
#pragma unroll
  for (int k = 0; k < 64; ++k) {
    const int u_s = (k + 32) & 63;
    const float wvv = (u_s >= s0 && u_s < e0) ? Wcp[(u_s << 6) + v_s] : 0.0f;
    buf[k][t] = Fre[k * 64 + t] * wvv;
  }
  __syncthreads();
  float re[64], im[64];
#pragma unroll
  for (int j = 0; j < 64; ++j) re[j] = buf[t][j];
  __syncthreads();
#pragma unroll
  for (int k = 0; k < 64; ++k) {
    const int u_s = (k + 32) & 63;
    const float wvv = (u_s >= s0 && u_s < e0) ? Wcp[(u_s << 6) + v_s] : 0.0f;
    buf[k][t] = Fim[k * 64 + t] * wvv;
  }
  __syncthreads();
#pragma unroll
  for (int j = 0; j < 64; ++j) im[j] = buf[t][j];
  fft64_regs<true>(re, im);  // row inverse FFTs
  // transpose (two passes)
#pragma unroll
  for (int j = 0; j < 64; ++j) buf[t][j] = re[j];
  __syncthreads();
#pragma unroll
  for (int j = 0; j < 64; ++j) re[j] = buf[j][t];
  __syncthreads();
#pragma unroll
  for (int j = 0; j < 64; ++j) buf[t][j] = im[j];
  __syncthreads();
#pragma unroll
  for (int j = 0; j < 64; ++j) im[j] = buf[j][t];
  fft64_regs<true>(re, im);  // column inverse FFTs; thread t holds column t
  const float mixv = mixp[0];
  const float sc = mixv * (1.0f / 4096.0f);
  const float om = 1.0f - mixv;
  float* op = out + ((size_t)img << 12);
  const float* xp = xsp + ((size_t)b << 12);
#pragma unroll
  for (int j = 0; j < 64; ++j)
    op[j * 64 + t] = fmaf(sc, re[j], om * xp[j * 64 + t]);
}

// ---------------------------------------------------------------------------
// Workspace layout (~131 MB):
//   [0, 128MB)        F    planar slots: active {Fre,Fim}, inactive {|F|}
//   [+128MB, +129MB)  Wc   float[64*64*64]
//   [+129MB, +130MB)  xsp  float[64*64*64]
//   [+130MB, +512B)   idx  int[128]
//   [+130MB+4KB, ..)  w1T  float[64*64]
// ---------------------------------------------------------------------------
extern "C" void kernel_launch(void* const* d_in, const int* in_sizes, int n_in,
                              void* d_out, int out_size, void* d_ws, size_t ws_size,
                              hipStream_t stream) {
  const float* x      = (const float*)d_in[0];
  const float* f0     = (const float*)d_in[1];
  const float* theta  = (const float*)d_in[2];
  const float* sigma  = (const float*)d_in[3];
  const float* theta0 = (const float*)d_in[4];
  const float* fbs    = (const float*)d_in[5];
  const float* mix    = (const float*)d_in[6];
  const float* w1     = (const float*)d_in[7];
  const float* b1     = (const float*)d_in[8];
  const float* w2     = (const float*)d_in[9];
  const float* b2     = (const float*)d_in[10];
  const float* cw     = (const float*)d_in[11];
  float* out = (float*)d_out;
  char* ws = (char*)d_ws;
  float* F   = (float*)(ws);
  float* Wc  = (float*)(ws + 134217728);
  float* xsp = (float*)(ws + 134217728 + 1048576);
  int* idx   = (int*)(ws + 134217728 + 2097152);
  float* w1T = (float*)(ws + 134217728 + 2097152 + 4096);

  k_setup<<<1, 64, 0, stream>>>(fbs, w1, idx, w1T);
  k_fft_fwd<<<4096, 64, 0, stream>>>(x, F, idx);
  k_attn<<<1024, 256, 0, stream>>>(F, w1T, b1, w2, b2, f0, theta, sigma, theta0, idx, Wc);
  k_conv<<<1024, 256, 0, stream>>>(x, cw, idx, mix, xsp, out);
  k_ifft_act<<<4096, 64, 0, stream>>>(F, Wc, xsp, idx, mix, out);
}

// Round 7
// 260.715 us; speedup vs baseline: 1.5518x; 1.0832x over previous
//
#include <hip/hip_runtime.h>

#define PI_D 3.14159265358979323846

// ---------------------------------------------------------------------------
// Compile-time twiddle tables: CT[k]=cos(2*pi*k/64), STb[k]=sin(2*pi*k/64).
// ---------------------------------------------------------------------------
namespace {
constexpr float CT[33] = {
  1.0000000000f,  0.9951847267f,  0.9807852804f,  0.9569403357f,
  0.9238795325f,  0.8819212643f,  0.8314696123f,  0.7730104534f,
  0.7071067812f,  0.6343932842f,  0.5555702330f,  0.4713967368f,
  0.3826834324f,  0.2902846773f,  0.1950903220f,  0.0980171403f,
  0.0f,          -0.0980171403f, -0.1950903220f, -0.2902846773f,
 -0.3826834324f, -0.4713967368f, -0.5555702330f, -0.6343932842f,
 -0.7071067812f, -0.7730104534f, -0.8314696123f, -0.8819212643f,
 -0.9238795325f, -0.9569403357f, -0.9807852804f, -0.9951847267f,
 -1.0f};
constexpr float STb[33] = {
  0.0f,           0.0980171403f,  0.1950903220f,  0.2902846773f,
  0.3826834324f,  0.4713967368f,  0.5555702330f,  0.6343932842f,
  0.7071067812f,  0.7730104534f,  0.8314696123f,  0.8819212643f,
  0.9238795325f,  0.9569403357f,  0.9807852804f,  0.9951847267f,
  1.0f,           0.9951847267f,  0.9807852804f,  0.9569403357f,
  0.9238795325f,  0.8819212643f,  0.8314696123f,  0.7730104534f,
  0.7071067812f,  0.6343932842f,  0.5555702330f,  0.4713967368f,
  0.3826834324f,  0.2902846773f,  0.1950903220f,  0.0980171403f,
  0.0f};
}

// In-register 64-point radix-2 DIT FFT, twiddles as literals.
template <bool INV>
__device__ __forceinline__ void fft64_regs(float re[64], float im[64]) {
#pragma unroll
  for (int i = 0; i < 64; ++i) {
    unsigned j = __brev((unsigned)i) >> 26;
    if ((int)j > i) {
      float tr = re[i]; re[i] = re[j]; re[j] = tr;
      float ti = im[i]; im[i] = im[j]; im[j] = ti;
    }
  }
#pragma unroll
  for (int s = 0; s < 6; ++s) {
    const int half = 1 << s;
    const int m = half << 1;
    const int tstep = 32 >> s;  // 64/m
#pragma unroll
    for (int k = 0; k < 64; k += m) {
#pragma unroll
      for (int j = 0; j < half; ++j) {
        const int ti = j * tstep;  // 0..31, compile-time
        const float wr = CT[ti];
        const float wi = INV ? STb[ti] : -STb[ti];
        const int a = k + j, b = k + j + half;
        const float tr = re[b] * wr - im[b] * wi;
        const float tii = re[b] * wi + im[b] * wr;
        re[b] = re[a] - tr; im[b] = im[a] - tii;
        re[a] = re[a] + tr; im[a] = im[a] + tii;
      }
    }
  }
}

// ---------------------------------------------------------------------------
// K0: frequency-band indices from fbs + w1 transpose (w1T[c][k] = w1[k][c]).
// ---------------------------------------------------------------------------
__global__ void k_setup(const float* __restrict__ fbs, const float* __restrict__ w1,
                        int* __restrict__ idx, float* __restrict__ w1T) {
  const int t = threadIdx.x;  // 64 threads
  idx[t]      = (int)floorf((fbs[2 * t]     + 1.0f) * 0.5f * 64.0f);
  idx[64 + t] = (int)floorf((fbs[2 * t + 1] + 1.0f) * 0.5f * 64.0f);
  for (int k = 0; k < 64; ++k) w1T[t * 64 + k] = w1[k * 64 + t];
}

// ---------------------------------------------------------------------------
// K1: forward FFT2 per (b,i) image. One wave per image. PLANAR output per
// 32KB slot: active (~8%) -> Fre @ +0, Fim @ +16KB; inactive -> |F| @ +0.
// ---------------------------------------------------------------------------
__global__ __launch_bounds__(64) void k_fft_fwd(const float* __restrict__ x,
                                                float* __restrict__ F,
                                                const int* __restrict__ idx) {
  __shared__ float buf[64][65];  // stride 65: (t+j)%32 banks -> 2-way (free)
  const int t = threadIdx.x;
  const int img = blockIdx.x;
  const float* xp = x + ((size_t)img << 12);
#pragma unroll
  for (int k = 0; k < 64; ++k) buf[k][t] = xp[k * 64 + t];  // coalesced stage
  __syncthreads();
  float re[64], im[64];
#pragma unroll
  for (int j = 0; j < 64; ++j) { re[j] = buf[t][j]; im[j] = 0.0f; }  // row t
  fft64_regs<false>(re, im);
  // transpose, two passes through the single buffer (row-private writes)
#pragma unroll
  for (int j = 0; j < 64; ++j) buf[t][j] = re[j];
  __syncthreads();
#pragma unroll
  for (int j = 0; j < 64; ++j) re[j] = buf[j][t];
  __syncthreads();
#pragma unroll
  for (int j = 0; j < 64; ++j) buf[t][j] = im[j];
  __syncthreads();
#pragma unroll
  for (int j = 0; j < 64; ++j) im[j] = buf[j][t];
  fft64_regs<false>(re, im);  // column FFT; thread t now holds column t
  const int b = img >> 6, i = img & 63;
  const int b_s = (b + 32) & 63, i_s = (i + 32) & 63;
  const int s0 = idx[b_s], e0 = idx[64 + b_s];
  float* Fre = F + ((size_t)img << 13);  // slot = 8192 floats
  if ((i_s >= s0) && (i_s < e0)) {  // active: planar complex
    float* Fim = Fre + 4096;
#pragma unroll
    for (int j = 0; j < 64; ++j) {
      Fre[j * 64 + t] = re[j];
      Fim[j * 64 + t] = im[j];
    }
  } else {  // inactive: magnitudes only
#pragma unroll
    for (int j = 0; j < 64; ++j)
      Fre[j * 64 + t] = sqrtf(re[j] * re[j] + im[j] * im[j]);
  }
}

// ---------------------------------------------------------------------------
// K2 v5: attention. 4096 blocks x 128 threads; block = (i, row h); lane = w;
// wave wv (SGPR via readfirstlane -- R5 showed threadIdx-derived addressing
// kills s_load uniformity: SGPR 112->32, 2x slower) handles c in
// [wv*32, wv*32+32). c-outer / k-inner, 64 independent acc chains (ILP=64).
// The contiguous active band [s0,e0) is handled by SEGMENTED runtime-uniform
// loops (mag | complex+sqrt | mag): no per-c branches to block load batching,
// and no reads of the unwritten Fim plane for inactive channels (R6 read 0xAA
// poison: FETCH 65 MB vs 35). Wave 1's partials combine via 17.4 KB LDS ->
// 8192 waves total (grid capped occupancy at 50% before).
// ---------------------------------------------------------------------------
__global__ __launch_bounds__(128) void k_attn(
    const float* __restrict__ F, const float* __restrict__ w1T,
    const float* __restrict__ b1, const float* __restrict__ w2,
    const float* __restrict__ b2, const float* __restrict__ f0,
    const float* __restrict__ theta, const float* __restrict__ sigma,
    const float* __restrict__ theta0, const int* __restrict__ idx,
    float* __restrict__ Wc) {
  __shared__ float4 part4[64][17];  // wave1 partials; stride 17*16B: no conflict
  const int t = threadIdx.x;
  const int lane = t & 63;                                   // = w
  const int wv = __builtin_amdgcn_readfirstlane(t >> 6);     // 0/1, SGPR
  const int i = blockIdx.x >> 6;                             // attn channel
  const int h = blockIdx.x & 63;                             // row
  const int b_f = (i + 32) & 63;
  const int u_f = (h + 32) & 63;
  const int v_f = (lane + 32) & 63;
  const int pos_f = (u_f << 6) + v_f;
  const int s0a = idx[i], e0a = idx[64 + i];
  // this wave's c range [c0, c1), split at the active band (uniform scalars)
  const int c0 = wv << 5, c1 = c0 + 32;
  int alo = s0a < c0 ? c0 : (s0a > c1 ? c1 : s0a);
  int ahi = e0a < c0 ? c0 : (e0a > c1 ? c1 : e0a);
  if (ahi < alo) ahi = alo;  // empty band when e<=s
  float acc[64];
#pragma unroll
  for (int k = 0; k < 64; ++k) acc[k] = 0.0f;
  const float* Fb = F + ((size_t)(b_f << 6) << 13) + pos_f;
  // --- segment 1: [c0, alo) magnitudes ---
#pragma unroll 4
  for (int c = c0; c < alo; ++c) {
    const int c_f = (c + 32) & 63;
    const float mc = Fb[(size_t)c_f << 13];
    const float* wrow = w1T + (c << 6);  // uniform -> s_load
#pragma unroll
    for (int k = 0; k < 64; ++k) acc[k] = fmaf(wrow[k], mc, acc[k]);
  }
  // --- segment 2: [alo, ahi) complex + sqrt ---
#pragma unroll 2
  for (int c = alo; c < ahi; ++c) {
    const int c_f = (c + 32) & 63;
    const float* base = Fb + ((size_t)c_f << 13);
    const float xr = base[0], xi = base[4096];
    const float mc = sqrtf(xr * xr + xi * xi);
    const float* wrow = w1T + (c << 6);
#pragma unroll
    for (int k = 0; k < 64; ++k) acc[k] = fmaf(wrow[k], mc, acc[k]);
  }
  // --- segment 3: [ahi, c1) magnitudes ---
#pragma unroll 4
  for (int c = ahi; c < c1; ++c) {
    const int c_f = (c + 32) & 63;
    const float mc = Fb[(size_t)c_f << 13];
    const float* wrow = w1T + (c << 6);
#pragma unroll
    for (int k = 0; k < 64; ++k) acc[k] = fmaf(wrow[k], mc, acc[k]);
  }
  if (wv != 0) {
#pragma unroll
    for (int kk = 0; kk < 16; ++kk)
      part4[lane][kk] = make_float4(acc[4 * kk], acc[4 * kk + 1],
                                    acc[4 * kk + 2], acc[4 * kk + 3]);
  }
  __syncthreads();
  if (wv != 0) return;  // uniform exit
#pragma unroll
  for (int kk = 0; kk < 16; ++kk) {
    const float4 p = part4[lane][kk];
    acc[4 * kk] += p.x; acc[4 * kk + 1] += p.y;
    acc[4 * kk + 2] += p.z; acc[4 * kk + 3] += p.w;
  }
  float l0 = b2[0], l1 = b2[1], l2 = b2[2];
#pragma unroll
  for (int k = 0; k < 64; ++k) {
    const float hv = fmaxf(acc[k] + b1[k], 0.0f);
    l0 = fmaf(w2[k], hv, l0);  // w2 layout [S=3][HID=64]
    l1 = fmaf(w2[64 + k], hv, l1);
    l2 = fmaf(w2[128 + k], hv, l2);
  }
  float mx = fmaxf(l0, fmaxf(l1, l2));
  float e0 = expf(l0 - mx), e1 = expf(l1 - mx), e2 = expf(l2 - mx);
  float inv = 1.0f / (e0 + e1 + e2);
  float aw0 = e0 * inv, aw1 = e1 * inv, aw2 = e2 * inv;
  const float yy = -1.0f + (float)h * (2.0f / 63.0f);
  const float xx = -1.0f + (float)lane * (2.0f / 63.0f);
  const float r = sqrtf(xx * xx + yy * yy + 1e-6f);
  const float lr = logf(r);
  const float phi = atan2f(yy, xx);
  float wc = 0.0f;
  const float aws[3] = {aw0, aw1, aw2};
#pragma unroll
  for (int s = 0; s < 3; ++s) {
    const float f0v = f0[s * 64 + i];  // [S][O=1][I]
    const float sgv = sigma[s * 64 + i];
    const float thv = theta[s * 64 + i];
    const float t0v = theta0[s * 64 + i];
    const float ls = logf(sgv);
    const float d1 = lr - logf(f0v);
    const float g1 = expf(-(d1 * d1) / (2.0f * ls * ls));
    const float d2 = phi - thv;
    const float g2 = expf(-(d2 * d2) / (2.0f * t0v * t0v));
    wc = fmaf(g1 * g2, aws[s], wc);
  }
  Wc[((i << 6) + h) * 64 + lane] = wc;
}

// ---------------------------------------------------------------------------
// K3: spatial 3x3 conv (wave per output row, shuffle-assembled neighbors)
// FUSED with the inactive-image output write.
// ---------------------------------------------------------------------------
__global__ __launch_bounds__(256) void k_conv(const float* __restrict__ x,
                                              const float* __restrict__ cw,
                                              const int* __restrict__ idx,
                                              const float* __restrict__ mixp,
                                              float* __restrict__ xsp,
                                              float* __restrict__ out) {
  __shared__ float wsm[576];
  const int t = threadIdx.x;
  for (int q = t; q < 576; q += 256) wsm[q] = cw[q];
  __syncthreads();
  const int lane = t & 63;
  const int wv = t >> 6;
  const int b = blockIdx.x >> 4;
  const int row = ((blockIdx.x & 15) << 2) | wv;
  const float* xb = x + ((size_t)b << 18);
  const int rm = row > 0 ? row - 1 : 0;  // clamped (masked in epilogue)
  const int rp = row < 63 ? row + 1 : 63;
  float P00 = 0.f, P01 = 0.f, P02 = 0.f;
  float P10 = 0.f, P11 = 0.f, P12 = 0.f;
  float P20 = 0.f, P21 = 0.f, P22 = 0.f;
#pragma unroll 4
  for (int ch = 0; ch < 64; ++ch) {
    const float* xc = xb + (ch << 12);
    const float v0 = xc[(rm << 6) + lane];
    const float v1 = xc[(row << 6) + lane];
    const float v2 = xc[(rp << 6) + lane];
    const float* wp = &wsm[ch * 9];
    P00 = fmaf(v0, wp[0], P00);
    P01 = fmaf(v0, wp[1], P01);
    P02 = fmaf(v0, wp[2], P02);
    P10 = fmaf(v1, wp[3], P10);
    P11 = fmaf(v1, wp[4], P11);
    P12 = fmaf(v1, wp[5], P12);
    P20 = fmaf(v2, wp[6], P20);
    P21 = fmaf(v2, wp[7], P21);
    P22 = fmaf(v2, wp[8], P22);
  }
  const float tmask = (row > 0) ? 1.0f : 0.0f;
  const float bmask = (row < 63) ? 1.0f : 0.0f;
  const float Ql = tmask * P00 + P10 + bmask * P20;
  const float Qm = tmask * P01 + P11 + bmask * P21;
  const float Qr = tmask * P02 + P12 + bmask * P22;
  const float fromL = __shfl_up(Ql, 1, 64);
  const float fromR = __shfl_down(Qr, 1, 64);
  float acc = Qm;
  if (lane > 0) acc += fromL;
  if (lane < 63) acc += fromR;
  xsp[((size_t)b << 12) + (row << 6) + lane] = acc;
  // Fused inactive-output epilogue (block-uniform per-i predicate).
  const int b_s = (b + 32) & 63;
  const int s0 = idx[b_s], e0 = idx[64 + b_s];
  const float val = (1.0f - mixp[0]) * acc;
  float* ob = out + ((size_t)b << 18) + (row << 6) + lane;
#pragma unroll 4
  for (int i2 = 0; i2 < 64; ++i2) {
    const int i_s = (i2 + 32) & 63;
    if (!(i_s >= s0 && i_s < e0)) ob[(size_t)i2 << 12] = val;
  }
}

// ---------------------------------------------------------------------------
// K4: ACTIVE images only (~8%): G = F*Wc(shifted)*rowmask; IFFT2; real part;
// mix with conv path. Inactive blocks exit immediately.
// ---------------------------------------------------------------------------
__global__ __launch_bounds__(64) void k_ifft_act(
    const float* __restrict__ F, const float* __restrict__ Wc,
    const float* __restrict__ xsp, const int* __restrict__ idx,
    const float* __restrict__ mixp, float* __restrict__ out) {
  const int img = blockIdx.x;
  const int b = img >> 6, i = img & 63;
  const int b_s = (b + 32) & 63, i_s = (i + 32) & 63;
  const int s0 = idx[b_s], e0 = idx[64 + b_s];
  if (!((i_s >= s0) && (i_s < e0))) return;  // inactive: handled by k_conv
  __shared__ float buf[64][65];
  const int t = threadIdx.x;
  const float* Fre = F + ((size_t)img << 13);
  const float* Fim = Fre + 4096;
  const float* Wcp = Wc + ((size_t)i_s << 12);
  const int v_s = (t + 32) & 63;
  // stage re rows (apply Wc * row-mask during staging)
#pragma unroll
  for (int k = 0; k < 64; ++k) {
    const int u_s = (k + 32) & 63;
    const float wvv = (u_s >= s0 && u_s < e0) ? Wcp[(u_s << 6) + v_s] : 0.0f;
    buf[k][t] = Fre[k * 64 + t] * wvv;
  }
  __syncthreads();
  float re[64], im[64];
#pragma unroll
  for (int j = 0; j < 64; ++j) re[j] = buf[t][j];
  __syncthreads();
#pragma unroll
  for (int k = 0; k < 64; ++k) {
    const int u_s = (k + 32) & 63;
    const float wvv = (u_s >= s0 && u_s < e0) ? Wcp[(u_s << 6) + v_s] : 0.0f;
    buf[k][t] = Fim[k * 64 + t] * wvv;
  }
  __syncthreads();
#pragma unroll
  for (int j = 0; j < 64; ++j) im[j] = buf[t][j];
  fft64_regs<true>(re, im);  // row inverse FFTs
  // transpose (two passes)
#pragma unroll
  for (int j = 0; j < 64; ++j) buf[t][j] = re[j];
  __syncthreads();
#pragma unroll
  for (int j = 0; j < 64; ++j) re[j] = buf[j][t];
  __syncthreads();
#pragma unroll
  for (int j = 0; j < 64; ++j) buf[t][j] = im[j];
  __syncthreads();
#pragma unroll
  for (int j = 0; j < 64; ++j) im[j] = buf[j][t];
  fft64_regs<true>(re, im);  // column inverse FFTs; thread t holds column t
  const float mixv = mixp[0];
  const float sc = mixv * (1.0f / 4096.0f);
  const float om = 1.0f - mixv;
  float* op = out + ((size_t)img << 12);
  const float* xp = xsp + ((size_t)b << 12);
#pragma unroll
  for (int j = 0; j < 64; ++j)
    op[j * 64 + t] = fmaf(sc, re[j], om * xp[j * 64 + t]);
}

// ---------------------------------------------------------------------------
// Workspace layout (~131 MB):
//   [0, 128MB)        F    planar slots: active {Fre,Fim}, inactive {|F|}
//   [+128MB, +129MB)  Wc   float[64*64*64]
//   [+129MB, +130MB)  xsp  float[64*64*64]
//   [+130MB, +512B)   idx  int[128]
//   [+130MB+4KB, ..)  w1T  float[64*64]
// ---------------------------------------------------------------------------
extern "C" void kernel_launch(void* const* d_in, const int* in_sizes, int n_in,
                              void* d_out, int out_size, void* d_ws, size_t ws_size,
                              hipStream_t stream) {
  const float* x      = (const float*)d_in[0];
  const float* f0     = (const float*)d_in[1];
  const float* theta  = (const float*)d_in[2];
  const float* sigma  = (const float*)d_in[3];
  const float* theta0 = (const float*)d_in[4];
  const float* fbs    = (const float*)d_in[5];
  const float* mix    = (const float*)d_in[6];
  const float* w1     = (const float*)d_in[7];
  const float* b1     = (const float*)d_in[8];
  const float* w2     = (const float*)d_in[9];
  const float* b2     = (const float*)d_in[10];
  const float* cw     = (const float*)d_in[11];
  float* out = (float*)d_out;
  char* ws = (char*)d_ws;
  float* F   = (float*)(ws);
  float* Wc  = (float*)(ws + 134217728);
  float* xsp = (float*)(ws + 134217728 + 1048576);
  int* idx   = (int*)(ws + 134217728 + 2097152);
  float* w1T = (float*)(ws + 134217728 + 2097152 + 4096);

  k_setup<<<1, 64, 0, stream>>>(fbs, w1, idx, w1T);
  k_fft_fwd<<<4096, 64, 0, stream>>>(x, F, idx);
  k_attn<<<4096, 128, 0, stream>>>(F, w1T, b1, w2, b2, f0, theta, sigma, theta0, idx, Wc);
  k_conv<<<1024, 256, 0, stream>>>(x, cw, idx, mix, xsp, out);
  k_ifft_act<<<4096, 64, 0, stream>>>(F, Wc, xsp, idx, mix, out);
}